// Round 17
// baseline (280.655 us; speedup 1.0000x reference)
//
#include <hip/hip_runtime.h>
#include <math.h>

#define HEADS 4
#define DHEAD 128
#define NPOS  4096      // 64*64 spatial positions
#define CIN   256
#define SCALEF 0.08838834764831845f   // 128^-0.5
#define LOG2E  1.4426950408889634f
#define QSCALE (SCALEF * LOG2E)       // folded: exp(sim) == exp2(sim * log2e)

typedef _Float16 half8  __attribute__((ext_vector_type(8)));
typedef _Float16 half4  __attribute__((ext_vector_type(4)));
typedef _Float16 half2v __attribute__((ext_vector_type(2)));
typedef float    f32x4  __attribute__((ext_vector_type(4)));

// Fragment layout for a matrix consumed as a 16x16x32 MFMA operand:
//   frag[rowtile = row>>4][kb = col>>5][lane = ((col>>3)&3)*16 + (row&15)][elem = col&7]
// One (rowtile,kb) slab = 64 lanes * 8 halves = 1 KiB contiguous.
#define FRAG_HEAD_HALVES (256 * 4 * 512)   // 524288 halves = 1 MB per head

// ---------------------------------------------------------------------------
// Kernel 0: convert W -> fp16 (QSCALE folded into Q rows), fmap -> fp16
// transposed [p][c] for proj's B-operand.
// ---------------------------------------------------------------------------
__global__ __launch_bounds__(256) void cvt_kernel(const float* __restrict__ fmap,
                                                  const float* __restrict__ W,
                                                  _Float16* __restrict__ W16,
                                                  _Float16* __restrict__ fmapT) {
  if (blockIdx.x < 16) {
    int base = blockIdx.x * 16384 + threadIdx.x;
#pragma unroll
    for (int t = 0; t < 64; ++t) {
      int idx = base + t * 256;
      float v = W[idx];
      W16[idx] = (_Float16)(idx < 512 * CIN ? v * QSCALE : v);
    }
  } else {
    int tile = blockIdx.x - 16;       // 64 p-tiles x 4 c-tiles
    int p0 = (tile >> 2) * 64, c0 = (tile & 3) * 64;
    __shared__ float t_lds[64][65];
    int tid = threadIdx.x;
#pragma unroll
    for (int t = 0; t < 16; ++t) {
      int lin = tid + t * 256;
      int r = lin >> 6, col = lin & 63;
      t_lds[r][col] = fmap[(size_t)(c0 + r) * NPOS + p0 + col];
    }
    __syncthreads();
#pragma unroll
    for (int t = 0; t < 16; ++t) {
      int lin = tid + t * 256;
      int pr = lin >> 6, cc = lin & 63;
      fmapT[(size_t)(p0 + pr) * CIN + c0 + cc] = (_Float16)t_lds[cc][pr];
    }
  }
}

// ---------------------------------------------------------------------------
// Kernel 1: projection GEMM.  qk[o][p] = sum_c W16[o][c]*fmapT[p][c]
// Output written in FRAGMENT layout (qf / kf) for the attn kernel.
// ---------------------------------------------------------------------------
__global__ __launch_bounds__(256) void proj_mfma(const _Float16* __restrict__ W16,
                                                 const _Float16* __restrict__ fmapT,
                                                 _Float16* __restrict__ qf,
                                                 _Float16* __restrict__ kf) {
  const int p0 = blockIdx.x * 64;
  const int o0 = blockIdx.y * 64 + (threadIdx.x >> 6) * 16;
  const int l = threadIdx.x & 63;
  const int lr = l & 15, lg = l >> 4;

  const f32x4 z = {0.f, 0.f, 0.f, 0.f};
  f32x4 acc[4] = {z, z, z, z};
#pragma unroll
  for (int kb = 0; kb < 8; ++kb) {
    half8 a = *(const half8*)(W16 + (size_t)(o0 + lr) * CIN + kb * 32 + lg * 8);
#pragma unroll
    for (int j = 0; j < 4; ++j) {
      half8 b = *(const half8*)(fmapT + (size_t)(p0 + j * 16 + lr) * CIN + kb * 32 + lg * 8);
      acc[j] = __builtin_amdgcn_mfma_f32_16x16x32_f16(a, b, acc[j], 0, 0, 0);
    }
  }
  // C/D: col(p) = lr, row(o) = lg*4 + r.  4 consecutive d per lane.
  const int ob = o0 + lg * 4;
  const bool isq = ob < 512;
  const int oo = isq ? ob : ob - 512;
  const int h = oo >> 7, db = oo & 127;        // d base, multiple of 4
  const int kb2 = db >> 5;                     // frag kb
  const int flane = ((db >> 3) & 3) * 16 + lr; // frag lane (lr = p&15)
  const int e0 = db & 7;                       // 0 or 4
  _Float16* dst = (isq ? qf : kf) + (size_t)h * FRAG_HEAD_HALVES;
#pragma unroll
  for (int j = 0; j < 4; ++j) {
    int pt = (p0 >> 4) + j;                    // position tile
    half4 v = {(_Float16)acc[j][0], (_Float16)acc[j][1],
               (_Float16)acc[j][2], (_Float16)acc[j][3]};
    *(half4*)(dst + ((size_t)pt * 4 + kb2) * 512 + flane * 8 + e0) = v;
  }
}

// ---------------------------------------------------------------------------
// Kernel 2: fused sim + softmax via MFMA, fragment-layout operands.
// R10 structure (512 thr / 8 waves / 512-col strips, register K loads, XCD
// swizzle, exp2, setprio, normal stores) + __launch_bounds__(512, 6): caps
// VGPR at ~85 so THREE blocks fit per CU (24 waves) instead of two.  More
// TLP hides K-load latency, and cross-block phase diversity lets one block's
// store burst overlap another block's compute.  Expected spill: a few of the
// write-once/read-once Pst values (cheapest possible spill victims).
// ---------------------------------------------------------------------------
#define QROWS 16
#define NTIL  32    // 512 cols per wave strip

__global__ __launch_bounds__(512, 6) void attn_mfma(const _Float16* __restrict__ qf,
                                                    const _Float16* __restrict__ kf,
                                                    float* __restrict__ out) {
  // XCD-locality decode (bijective: 1024 blocks, 1024 % 8 == 0)
  const int b = blockIdx.x;            // 0..1023
  const int h = (b & 7) >> 1;          // head on XCD pair {2h, 2h+1}
  const int qtile = ((b >> 3) << 1) | (b & 1);   // 0..255, bijective per head
  const int i0 = qtile * QROWS;

  const int wv = threadIdx.x >> 6;
  const int l = threadIdx.x & 63;
  const int lr = l & 15, lg = l >> 4;

  const _Float16* Qf = qf + (size_t)h * FRAG_HEAD_HALVES;
  const _Float16* Kf = kf + (size_t)h * FRAG_HEAD_HALVES;

  // A fragments (Q row-tile i0>>4), hoisted
  half8 afr[4];
#pragma unroll
  for (int kb = 0; kb < 4; ++kb)
    afr[kb] = *(const half8*)(Qf + ((size_t)(i0 >> 4) * 4 + kb) * 512 + l * 8);

  const int jt0 = wv * NTIL;      // first column tile for this wave
  half2v Pst[2 * NTIL];
  float rs[4] = {0.f, 0.f, 0.f, 0.f};
  const f32x4 z = {0.f, 0.f, 0.f, 0.f};

#pragma unroll
  for (int t = 0; t < NTIL; ++t) {
    const _Float16* kp = Kf + ((size_t)(jt0 + t) * 4) * 512 + l * 8;
    half8 b0 = *(const half8*)(kp);
    half8 b1 = *(const half8*)(kp + 512);
    half8 b2 = *(const half8*)(kp + 1024);
    half8 b3 = *(const half8*)(kp + 1536);
    f32x4 acc = z;
    __builtin_amdgcn_s_setprio(1);
    acc = __builtin_amdgcn_mfma_f32_16x16x32_f16(afr[0], b0, acc, 0, 0, 0);
    acc = __builtin_amdgcn_mfma_f32_16x16x32_f16(afr[1], b1, acc, 0, 0, 0);
    acc = __builtin_amdgcn_mfma_f32_16x16x32_f16(afr[2], b2, acc, 0, 0, 0);
    acc = __builtin_amdgcn_mfma_f32_16x16x32_f16(afr[3], b3, acc, 0, 0, 0);
    __builtin_amdgcn_s_setprio(0);
    // Q was pre-scaled by log2e: exp(sim) == exp2(acc), one v_exp each.
    float e0 = __builtin_amdgcn_exp2f(acc[0]);
    float e1 = __builtin_amdgcn_exp2f(acc[1]);
    float e2 = __builtin_amdgcn_exp2f(acc[2]);
    float e3 = __builtin_amdgcn_exp2f(acc[3]);
    rs[0] += e0; rs[1] += e1; rs[2] += e2; rs[3] += e3;
    Pst[2 * t]     = half2v{(_Float16)e0, (_Float16)e1};
    Pst[2 * t + 1] = half2v{(_Float16)e2, (_Float16)e3};
  }

  // Row sums: reduce across the 16 lanes (lr bits) of each row group
#pragma unroll
  for (int off = 1; off < 16; off <<= 1) {
#pragma unroll
    for (int r = 0; r < 4; ++r) rs[r] += __shfl_xor(rs[r], off);
  }
  __shared__ float red[8][16];
  if (lr == 0) {
#pragma unroll
    for (int r = 0; r < 4; ++r) red[wv][lg * 4 + r] = rs[r];
  }
  __syncthreads();
  float inv[4];
#pragma unroll
  for (int r = 0; r < 4; ++r) {
    float s = 0.f;
#pragma unroll
    for (int w = 0; w < 8; ++w) s += red[w][lg * 4 + r];
    inv[r] = 1.0f / s;
  }

  // Normalized write (normal stores). row = lg*4 + r, col = (jt0+t)*16 + lr.
  float* ob = out + ((size_t)h * NPOS + i0) * NPOS + jt0 * 16;
#pragma unroll
  for (int t = 0; t < NTIL; ++t) {
    float e[4] = {(float)Pst[2 * t][0], (float)Pst[2 * t][1],
                  (float)Pst[2 * t + 1][0], (float)Pst[2 * t + 1][1]};
#pragma unroll
    for (int r = 0; r < 4; ++r) {
      ob[(size_t)(lg * 4 + r) * NPOS + t * 16 + lr] = e[r] * inv[r];
    }
  }
}

extern "C" void kernel_launch(void* const* d_in, const int* in_sizes, int n_in,
                              void* d_out, int out_size, void* d_ws, size_t ws_size,
                              hipStream_t stream) {
  const float* fmap = (const float*)d_in[0];   // [1,256,64,64]
  const float* W    = (const float*)d_in[1];   // [1024,256]
  float* out = (float*)d_out;                  // [1,4,4096,4096]

  char* ws = (char*)d_ws;
  _Float16* qf    = (_Float16*)(ws);                    // 4 MB fragment layout
  _Float16* kf    = (_Float16*)(ws + (4u << 20));       // 4 MB fragment layout
  _Float16* W16   = (_Float16*)(ws + (8u << 20));       // 512 KB
  _Float16* fmapT = (_Float16*)(ws + (8u << 20) + (512u << 10)); // 2 MB

  cvt_kernel<<<272, 256, 0, stream>>>(fmap, W, W16, fmapT);
  proj_mfma<<<dim3(NPOS / 64, 1024 / 64), 256, 0, stream>>>(W16, fmapT, qf, kf);
  attn_mfma<<<NPOS / QROWS * HEADS, 512, 0, stream>>>(qf, kf, out);
}

// Round 18
// 105.445 us; speedup vs baseline: 2.6616x; 2.6616x over previous
//
#include <hip/hip_runtime.h>
#include <math.h>

#define HEADS 4
#define DHEAD 128
#define NPOS  4096      // 64*64 spatial positions
#define CIN   256
#define SCALEF 0.08838834764831845f   // 128^-0.5
#define LOG2E  1.4426950408889634f
#define QSCALE (SCALEF * LOG2E)       // folded: exp(sim) == exp2(sim * log2e)

typedef _Float16 half8  __attribute__((ext_vector_type(8)));
typedef _Float16 half4  __attribute__((ext_vector_type(4)));
typedef _Float16 half2v __attribute__((ext_vector_type(2)));
typedef float    f32x4  __attribute__((ext_vector_type(4)));

// Fragment layout for a matrix consumed as a 16x16x32 MFMA operand:
//   frag[rowtile = row>>4][kb = col>>5][lane = ((col>>3)&3)*16 + (row&15)][elem = col&7]
// One (rowtile,kb) slab = 64 lanes * 8 halves = 1 KiB contiguous -> both a
// 1 KiB wave load AND a valid global_load_lds dest (base + lane*16B).
#define FRAG_HEAD_HALVES (256 * 4 * 512)   // 524288 halves = 1 MB per head

// ---------------------------------------------------------------------------
// Kernel 0: convert W -> fp16 (QSCALE folded into Q rows), fmap -> fp16
// transposed [p][c] for proj's B-operand.
// ---------------------------------------------------------------------------
__global__ __launch_bounds__(256) void cvt_kernel(const float* __restrict__ fmap,
                                                  const float* __restrict__ W,
                                                  _Float16* __restrict__ W16,
                                                  _Float16* __restrict__ fmapT) {
  if (blockIdx.x < 16) {
    int base = blockIdx.x * 16384 + threadIdx.x;
#pragma unroll
    for (int t = 0; t < 64; ++t) {
      int idx = base + t * 256;
      float v = W[idx];
      W16[idx] = (_Float16)(idx < 512 * CIN ? v * QSCALE : v);
    }
  } else {
    int tile = blockIdx.x - 16;       // 64 p-tiles x 4 c-tiles
    int p0 = (tile >> 2) * 64, c0 = (tile & 3) * 64;
    __shared__ float t_lds[64][65];
    int tid = threadIdx.x;
#pragma unroll
    for (int t = 0; t < 16; ++t) {
      int lin = tid + t * 256;
      int r = lin >> 6, col = lin & 63;
      t_lds[r][col] = fmap[(size_t)(c0 + r) * NPOS + p0 + col];
    }
    __syncthreads();
#pragma unroll
    for (int t = 0; t < 16; ++t) {
      int lin = tid + t * 256;
      int pr = lin >> 6, cc = lin & 63;
      fmapT[(size_t)(p0 + pr) * CIN + c0 + cc] = (_Float16)t_lds[cc][pr];
    }
  }
}

// ---------------------------------------------------------------------------
// Kernel 1: projection GEMM.  qk[o][p] = sum_c W16[o][c]*fmapT[p][c]
// Output written in FRAGMENT layout (qf / kf) for the attn kernel.
// ---------------------------------------------------------------------------
__global__ __launch_bounds__(256) void proj_mfma(const _Float16* __restrict__ W16,
                                                 const _Float16* __restrict__ fmapT,
                                                 _Float16* __restrict__ qf,
                                                 _Float16* __restrict__ kf) {
  const int p0 = blockIdx.x * 64;
  const int o0 = blockIdx.y * 64 + (threadIdx.x >> 6) * 16;
  const int l = threadIdx.x & 63;
  const int lr = l & 15, lg = l >> 4;

  const f32x4 z = {0.f, 0.f, 0.f, 0.f};
  f32x4 acc[4] = {z, z, z, z};
#pragma unroll
  for (int kb = 0; kb < 8; ++kb) {
    half8 a = *(const half8*)(W16 + (size_t)(o0 + lr) * CIN + kb * 32 + lg * 8);
#pragma unroll
    for (int j = 0; j < 4; ++j) {
      half8 b = *(const half8*)(fmapT + (size_t)(p0 + j * 16 + lr) * CIN + kb * 32 + lg * 8);
      acc[j] = __builtin_amdgcn_mfma_f32_16x16x32_f16(a, b, acc[j], 0, 0, 0);
    }
  }
  // C/D: col(p) = lr, row(o) = lg*4 + r.  4 consecutive d per lane.
  const int ob = o0 + lg * 4;
  const bool isq = ob < 512;
  const int oo = isq ? ob : ob - 512;
  const int h = oo >> 7, db = oo & 127;        // d base, multiple of 4
  const int kb2 = db >> 5;                     // frag kb
  const int flane = ((db >> 3) & 3) * 16 + lr; // frag lane (lr = p&15)
  const int e0 = db & 7;                       // 0 or 4
  _Float16* dst = (isq ? qf : kf) + (size_t)h * FRAG_HEAD_HALVES;
#pragma unroll
  for (int j = 0; j < 4; ++j) {
    int pt = (p0 >> 4) + j;                    // position tile
    half4 v = {(_Float16)acc[j][0], (_Float16)acc[j][1],
               (_Float16)acc[j][2], (_Float16)acc[j][3]};
    *(half4*)(dst + ((size_t)pt * 4 + kb2) * 512 + flane * 8 + e0) = v;
  }
}

// ---------------------------------------------------------------------------
// Kernel 2: fused sim + softmax via MFMA.  (Best-known configuration, R12.)
// 512 thr / 8 waves / 512-col strips; K tiles staged through a per-wave
// double-buffered LDS region via global_load_lds DMA (no VGPR round-trip),
// counted s_waitcnt vmcnt(4) between tiles (vmcnt(0) only at the final tile);
// no barriers in the main loop (each wave owns its slab); XCD-locality
// swizzle; exp2 with log2e pre-folded into Q; setprio around MFMA clusters.
// ---------------------------------------------------------------------------
#define QROWS 16
#define NTIL  32

__global__ __launch_bounds__(512) void attn_mfma(const _Float16* __restrict__ qf,
                                                 const _Float16* __restrict__ kf,
                                                 float* __restrict__ out) {
  // XCD-locality decode (bijective: 1024 blocks, 1024 % 8 == 0)
  const int b = blockIdx.x;            // 0..1023
  const int h = (b & 7) >> 1;          // head on XCD pair {2h, 2h+1}
  const int qtile = ((b >> 3) << 1) | (b & 1);   // 0..255, bijective per head
  const int i0 = qtile * QROWS;

  const int wv = threadIdx.x >> 6;
  const int l = threadIdx.x & 63;
  const int lr = l & 15, lg = l >> 4;

  __shared__ __align__(16) _Float16 kstage[2][8][2048];  // 64 KB dbuf staging
  __shared__ float red[8][16];

  const _Float16* Qf = qf + (size_t)h * FRAG_HEAD_HALVES;
  const _Float16* Kf = kf + (size_t)h * FRAG_HEAD_HALVES;

  // A fragments (Q row-tile i0>>4), hoisted
  half8 afr[4];
#pragma unroll
  for (int kb = 0; kb < 4; ++kb)
    afr[kb] = *(const half8*)(Qf + ((size_t)(i0 >> 4) * 4 + kb) * 512 + l * 8);

  const int jt0 = wv * NTIL;      // first column tile for this wave
  const _Float16* kbase = Kf + (size_t)jt0 * 2048 + l * 8;  // per-lane addr

  half2v Pst[2 * NTIL];
  float rs[4] = {0.f, 0.f, 0.f, 0.f};
  const f32x4 z = {0.f, 0.f, 0.f, 0.f};

  // DMA one K tile (4 slabs x 1 KiB) into staging buffer `buf`.
#define DMA(buf, tt)                                                          \
  { const _Float16* kp_ = kbase + (size_t)(tt) * 2048;                        \
    __builtin_amdgcn_global_load_lds(                                         \
        (const __attribute__((address_space(1))) unsigned int*)(kp_),         \
        (__attribute__((address_space(3))) unsigned int*)(&kstage[buf][wv][0]), 16, 0, 0);  \
    __builtin_amdgcn_global_load_lds(                                         \
        (const __attribute__((address_space(1))) unsigned int*)(kp_ + 512),   \
        (__attribute__((address_space(3))) unsigned int*)(&kstage[buf][wv][512]), 16, 0, 0); \
    __builtin_amdgcn_global_load_lds(                                         \
        (const __attribute__((address_space(1))) unsigned int*)(kp_ + 1024),  \
        (__attribute__((address_space(3))) unsigned int*)(&kstage[buf][wv][1024]), 16, 0, 0); \
    __builtin_amdgcn_global_load_lds(                                         \
        (const __attribute__((address_space(1))) unsigned int*)(kp_ + 1536),  \
        (__attribute__((address_space(3))) unsigned int*)(&kstage[buf][wv][1536]), 16, 0, 0); }

#define COMPUTE(buf, tt)                                                      \
  { const _Float16* sp = &kstage[buf][wv][l * 8];                             \
    half8 b0 = *(const half8*)(sp);                                           \
    half8 b1 = *(const half8*)(sp + 512);                                     \
    half8 b2 = *(const half8*)(sp + 1024);                                    \
    half8 b3 = *(const half8*)(sp + 1536);                                    \
    f32x4 acc = z;                                                            \
    __builtin_amdgcn_s_setprio(1);                                            \
    acc = __builtin_amdgcn_mfma_f32_16x16x32_f16(afr[0], b0, acc, 0, 0, 0);   \
    acc = __builtin_amdgcn_mfma_f32_16x16x32_f16(afr[1], b1, acc, 0, 0, 0);   \
    acc = __builtin_amdgcn_mfma_f32_16x16x32_f16(afr[2], b2, acc, 0, 0, 0);   \
    acc = __builtin_amdgcn_mfma_f32_16x16x32_f16(afr[3], b3, acc, 0, 0, 0);   \
    __builtin_amdgcn_s_setprio(0);                                            \
    float e0 = __builtin_amdgcn_exp2f(acc[0]);                                \
    float e1 = __builtin_amdgcn_exp2f(acc[1]);                                \
    float e2 = __builtin_amdgcn_exp2f(acc[2]);                                \
    float e3 = __builtin_amdgcn_exp2f(acc[3]);                                \
    rs[0] += e0; rs[1] += e1; rs[2] += e2; rs[3] += e3;                       \
    Pst[2 * (tt)]     = half2v{(_Float16)e0, (_Float16)e1};                   \
    Pst[2 * (tt) + 1] = half2v{(_Float16)e2, (_Float16)e3}; }

  DMA(0, 0)
#pragma unroll
  for (int tp = 0; tp < NTIL; tp += 2) {
    DMA(1, tp + 1)                                     // always valid: NTIL even
    asm volatile("s_waitcnt vmcnt(4)" ::: "memory");   // tile tp landed
    COMPUTE(0, tp)
    if (tp + 2 < NTIL) {
      DMA(0, tp + 2)
      asm volatile("s_waitcnt vmcnt(4)" ::: "memory"); // tile tp+1 landed
    } else {
      asm volatile("s_waitcnt vmcnt(0)" ::: "memory"); // final drain
    }
    COMPUTE(1, tp + 1)
  }
#undef DMA
#undef COMPUTE

  // Row sums: reduce across the 16 lanes (lr bits) of each row group
#pragma unroll
  for (int off = 1; off < 16; off <<= 1) {
#pragma unroll
    for (int r = 0; r < 4; ++r) rs[r] += __shfl_xor(rs[r], off);
  }
  if (lr == 0) {
#pragma unroll
    for (int r = 0; r < 4; ++r) red[wv][lg * 4 + r] = rs[r];
  }
  __syncthreads();
  float inv[4];
#pragma unroll
  for (int r = 0; r < 4; ++r) {
    float s = 0.f;
#pragma unroll
    for (int w = 0; w < 8; ++w) s += red[w][lg * 4 + r];
    inv[r] = 1.0f / s;
  }

  // Normalized write (normal stores). row = lg*4 + r, col = (jt0+t)*16 + lr.
  float* ob = out + ((size_t)h * NPOS + i0) * NPOS + jt0 * 16;
#pragma unroll
  for (int t = 0; t < NTIL; ++t) {
    float e[4] = {(float)Pst[2 * t][0], (float)Pst[2 * t][1],
                  (float)Pst[2 * t + 1][0], (float)Pst[2 * t + 1][1]};
#pragma unroll
    for (int r = 0; r < 4; ++r) {
      ob[(size_t)(lg * 4 + r) * NPOS + t * 16 + lr] = e[r] * inv[r];
    }
  }
}

extern "C" void kernel_launch(void* const* d_in, const int* in_sizes, int n_in,
                              void* d_out, int out_size, void* d_ws, size_t ws_size,
                              hipStream_t stream) {
  const float* fmap = (const float*)d_in[0];   // [1,256,64,64]
  const float* W    = (const float*)d_in[1];   // [1024,256]
  float* out = (float*)d_out;                  // [1,4,4096,4096]

  char* ws = (char*)d_ws;
  _Float16* qf    = (_Float16*)(ws);                    // 4 MB fragment layout
  _Float16* kf    = (_Float16*)(ws + (4u << 20));       // 4 MB fragment layout
  _Float16* W16   = (_Float16*)(ws + (8u << 20));       // 512 KB
  _Float16* fmapT = (_Float16*)(ws + (8u << 20) + (512u << 10)); // 2 MB

  cvt_kernel<<<272, 256, 0, stream>>>(fmap, W, W16, fmapT);
  proj_mfma<<<dim3(NPOS / 64, 1024 / 64), 256, 0, stream>>>(W16, fmapT, qf, kf);
  attn_mfma<<<NPOS / QROWS * HEADS, 512, 0, stream>>>(qf, kf, out);
}